// Round 5
// baseline (10519.736 us; speedup 1.0000x reference)
//
#include <hip/hip_runtime.h>

typedef _Float16 f16;
typedef _Float16 f16x8 __attribute__((ext_vector_type(8)));
typedef float f32x4 __attribute__((ext_vector_type(4)));

#define STEPS 512
#define BATCHN 256
#define HID 1024
#define EMBN 100
#define KTOT 1152
#define XPAD 128
#define NBLK 256

__device__ __forceinline__ float sigm(float x){ return 1.f/(1.f+__expf(-x)); }
__device__ __forceinline__ float tanh_f(float x){
    float e = __expf(2.f*fabsf(x));
    float r = 1.f - 2.f/(e+1.f);
    return x >= 0.f ? r : -r;
}
// select {a0,a1,a2,a3}[idx] without runtime-indexed array (rule #20)
__device__ __forceinline__ float pick4(float a0, float a1, float a2, float a3, int idx){
    float t0 = (idx & 1) ? a1 : a0;
    float t1 = (idx & 1) ? a3 : a2;
    return (idx & 2) ? t1 : t0;
}

// Pack W_h(1024 rows)+W_x(100)+pad -> WT[4096][1152] f16 hi/lo.
// Col J = cg*64 + ct*16 + g*4 + um -> unit u = cg*16 + ct*4 + um. Also bias[J].
__global__ void pack_w(const float* __restrict__ Whi_, const float* __restrict__ Whf_,
                       const float* __restrict__ Who_, const float* __restrict__ Whc_,
                       const float* __restrict__ Wxi_, const float* __restrict__ Wxf_,
                       const float* __restrict__ Wxo_, const float* __restrict__ Wxc_,
                       const float* __restrict__ bi_, const float* __restrict__ bf_,
                       const float* __restrict__ bo_, const float* __restrict__ bc_,
                       f16* __restrict__ WThi, f16* __restrict__ WTlo, float* __restrict__ biasP)
{
    int J = blockIdx.x;                 // 0..4095
    int cg = J >> 6, ct = (J >> 4) & 3, g = (J >> 2) & 3, um = J & 3;
    int u = cg*16 + ct*4 + um;
    const float* Wh = (g==0)?Whi_:(g==1)?Whf_:(g==2)?Who_:Whc_;
    const float* Wx = (g==0)?Wxi_:(g==1)?Wxf_:(g==2)?Wxo_:Wxc_;
    for (int k = threadIdx.x; k < KTOT; k += blockDim.x){
        float v = 0.f;
        if (k < 1024)       v = Wh[(size_t)k*HID + u];
        else if (k < 1124)  v = Wx[(size_t)(k-1024)*HID + u];
        f16 hi = (f16)v;
        WThi[(size_t)J*KTOT + k] = hi;
        WTlo[(size_t)J*KTOT + k] = (f16)(v - (float)hi);
    }
    if (threadIdx.x == 0){
        const float* bb = (g==0)?bi_:(g==1)?bf_:(g==2)?bo_:bc_;
        biasP[J] = bb[u];
    }
}

__global__ void pack_x(const int* __restrict__ tokens, const float* __restrict__ emb,
                       f16* __restrict__ Xbuf)
{
    int bid = blockIdx.x;               // t*256 + row
    int t = bid >> 8, row = bid & 255;
    int tok = tokens[(size_t)row*STEPS + t];
    int kx = threadIdx.x;               // 0..127
    float v = (kx < EMBN) ? emb[(size_t)tok*EMBN + kx] : 0.f;
    Xbuf[(size_t)bid*XPAD + kx] = (f16)v;
}

__global__ void pack_h0(const float* __restrict__ H0, f16* __restrict__ Hb)
{
    int i = blockIdx.x*blockDim.x + threadIdx.x;
    if (i < BATCHN*HID) Hb[i] = (f16)H0[i];
}

// 3-deep pipelined A-tile load. H + X rows: PLAIN cached loads (L1/XCD-L2
// broadcast across the 64 blocks sharing a bg). Staleness handled by a
// per-step agent-scope acquire fence (buffer_inv) after the grid barrier.
#define ISSUE(kt_, AF) do {                                                              \
    const int kb_ = w*288 + (kt_)*32;                                                    \
    if (kb_ < 1024) {                                                                    \
        const f16* hb_ = Hrd + kb_ + lhi*8;                                              \
        asm volatile("global_load_dwordx4 %0, %1, off" : "=v"(AF[0]) : "v"(hb_ + (size_t)rA[0]*HID)); \
        asm volatile("global_load_dwordx4 %0, %1, off" : "=v"(AF[1]) : "v"(hb_ + (size_t)rA[1]*HID)); \
        asm volatile("global_load_dwordx4 %0, %1, off" : "=v"(AF[2]) : "v"(hb_ + (size_t)rA[2]*HID)); \
        asm volatile("global_load_dwordx4 %0, %1, off" : "=v"(AF[3]) : "v"(hb_ + (size_t)rA[3]*HID)); \
    } else {                                                                             \
        const f16* xb_ = Xrow + (kb_ - 1024) + lhi*8;                                    \
        asm volatile("global_load_dwordx4 %0, %1, off" : "=v"(AF[0]) : "v"(xb_ + (size_t)rA[0]*XPAD)); \
        asm volatile("global_load_dwordx4 %0, %1, off" : "=v"(AF[1]) : "v"(xb_ + (size_t)rA[1]*XPAD)); \
        asm volatile("global_load_dwordx4 %0, %1, off" : "=v"(AF[2]) : "v"(xb_ + (size_t)rA[2]*XPAD)); \
        asm volatile("global_load_dwordx4 %0, %1, off" : "=v"(AF[3]) : "v"(xb_ + (size_t)rA[3]*XPAD)); \
    }                                                                                    \
} while(0)

#define WAITK(kt_) do {                                                                  \
    if ((kt_) < 7)       asm volatile("s_waitcnt vmcnt(8)" ::: "memory");                \
    else if ((kt_) == 7) asm volatile("s_waitcnt vmcnt(4)" ::: "memory");                \
    else                 asm volatile("s_waitcnt vmcnt(0)" ::: "memory");                \
    __builtin_amdgcn_sched_barrier(0);                                                   \
} while(0)

#define MM(kt_, AF) do {                                                                 \
    _Pragma("unroll")                                                                    \
    for (int q_ = 0; q_ < 4; q_++){                                                      \
        _Pragma("unroll")                                                                \
        for (int ct_ = 0; ct_ < 4; ct_++){                                               \
            acc[q_][ct_] = __builtin_amdgcn_mfma_f32_16x16x32_f16(AF[q_], Bf[kt_][0][ct_], acc[q_][ct_], 0,0,0); \
            acc[q_][ct_] = __builtin_amdgcn_mfma_f32_16x16x32_f16(AF[q_], Bf[kt_][1][ct_], acc[q_][ct_], 0,0,0); \
        }                                                                                \
    }                                                                                    \
} while(0)

// Persistent LSTM: 256 blocks (4 batch-groups x 64 col-groups) x 256 threads, 1/CU.
// bg = bid&3 aligns with the round-robin bid->XCD mapping: each XCD hosts one bg,
// so its 32 blocks share one 147KB H-slice in XCD L2. Weights f16 hi/lo in
// VGPR+AGPR (288/lane). H stores + flags at device scope (sc1, LLC); H reads
// plain-cached with a per-step buffer_inv (acquire fence) after the barrier.
__global__ __launch_bounds__(256, 1) void lstm_main(
    const f16* __restrict__ WThi, const f16* __restrict__ WTlo,
    const f16* __restrict__ Xbuf, const float* __restrict__ biasP,
    const float* __restrict__ C0, f16* __restrict__ Ha, f16* __restrict__ Hb,
    const float* __restrict__ dw, const float* __restrict__ db,
    float* __restrict__ out, unsigned* __restrict__ flags)
{
    __shared__ f32x4 red[4*3*4*64];     // [owner][q1][ct][lane], 48KB
    __shared__ int s_bail;

    const int bid = blockIdx.x;
    const int bg = bid & 3, cg = bid >> 2;
    const int tid = threadIdx.x;
    const int w = tid >> 6, l = tid & 63, lr = l & 15, lhi = l >> 4;
    const int um = l & 3, gs = lr >> 2;
    if (tid == 0) s_bail = 0;

    // ---- persistent weights: 9 kt x {hi,lo} x 4 ct = 288 VGPR/AGPR per lane ----
    f16x8 Bf[9][2][4];
    #pragma unroll
    for (int kt = 0; kt < 9; kt++){
        int k0 = w*288 + kt*32 + lhi*8;
        #pragma unroll
        for (int ct = 0; ct < 4; ct++){
            size_t off = (size_t)(cg*64 + ct*16 + lr)*KTOT + k0;
            Bf[kt][0][ct] = *(const f16x8*)(WThi + off);
            Bf[kt][1][ct] = *(const f16x8*)(WTlo + off);
        }
    }
    float bs[4][4];                      // [ct][gate]
    #pragma unroll
    for (int ct = 0; ct < 4; ct++)
        #pragma unroll
        for (int g = 0; g < 4; g++)
            bs[ct][g] = biasP[cg*64 + ct*16 + g*4 + um];

    int rA[4];
    #pragma unroll
    for (int q = 0; q < 4; q++) rA[q] = bg*64 + ((w + q) & 3)*16 + lr;
    const int myrow0 = bg*64 + w*16 + lhi*4;      // kept rowtile = global rt w
    const int colW = cg*16 + gs*4 + um;           // H-store column

    float Cr[4][4];                      // [ct][r], gs-redundant
    #pragma unroll
    for (int ct = 0; ct < 4; ct++)
        #pragma unroll
        for (int r = 0; r < 4; r++)
            Cr[ct][r] = C0[(size_t)(myrow0 + r)*HID + cg*16 + ct*4 + um];

    __syncthreads();

    for (int t = 0; t < STEPS; t++){
        const f16* Hrd = (t & 1) ? Hb : Ha;
        f16*       Hwr = (t & 1) ? Ha : Hb;
        const f16* Xrow = Xbuf + (size_t)t*BATCHN*XPAD;

        f32x4 acc[4][4];
        #pragma unroll
        for (int q = 0; q < 4; q++)
            #pragma unroll
            for (int ct = 0; ct < 4; ct++) acc[q][ct] = (f32x4){0.f,0.f,0.f,0.f};

        f16x8 Aa[4], Ab[4], Ac[4];
        ISSUE(0, Aa);
        ISSUE(1, Ab);
        #pragma unroll
        for (int kt = 0; kt < 9; kt++){
            if ((kt % 3) == 0){
                if (kt < 7) ISSUE(kt+2, Ac);
                WAITK(kt); MM(kt, Aa);
            } else if ((kt % 3) == 1){
                if (kt < 7) ISSUE(kt+2, Aa);
                WAITK(kt); MM(kt, Ab);
            } else {
                if (kt < 7) ISSUE(kt+2, Ab);
                WAITK(kt); MM(kt, Ac);
            }
        }

        // ---- cross-wave K reduction (kept tile q=0 <-> global rt w) ----
        #pragma unroll
        for (int q = 1; q < 4; q++){
            int o = (w + q) & 3;
            #pragma unroll
            for (int ct = 0; ct < 4; ct++)
                red[((o*3 + (q-1))*4 + ct)*64 + l] = acc[q][ct];
        }
        __syncthreads();
        #pragma unroll
        for (int q1 = 0; q1 < 3; q1++)
            #pragma unroll
            for (int ct = 0; ct < 4; ct++)
                acc[0][ct] += red[((w*3 + q1)*4 + ct)*64 + l];

        // ---- epilogue: gather gates (xor 4/8/12), update C, compute h ----
        float hall[4][4];
        #pragma unroll
        for (int ct = 0; ct < 4; ct++){
            #pragma unroll
            for (int r = 0; r < 4; r++){
                float a0 = acc[0][ct][r];
                float a1 = __shfl_xor(a0, 4, 64);
                float a2 = __shfl_xor(a0, 8, 64);
                float a3 = __shfl_xor(a0, 12, 64);
                float gi = pick4(a0,a1,a2,a3, gs    ) + bs[ct][0];
                float gf = pick4(a0,a1,a2,a3, gs ^ 1) + bs[ct][1];
                float go = pick4(a0,a1,a2,a3, gs ^ 2) + bs[ct][2];
                float gc = pick4(a0,a1,a2,a3, gs ^ 3) + bs[ct][3];
                float I = sigm(gi), F = sigm(gf), O = sigm(go), G = tanh_f(gc);
                float c = F*Cr[ct][r] + I*G;
                Cr[ct][r] = c;
                hall[ct][r] = O*tanh_f(c);
            }
        }

        // ---- H store: lane gs stores ct=gs -> each (unit,row) exactly once.
        //      sc1 write-through to LLC (device scope). ----
        #pragma unroll
        for (int r = 0; r < 4; r++){
            float hv = pick4(hall[0][r], hall[1][r], hall[2][r], hall[3][r], gs);
            f16 h16 = (f16)hv;
            f16* p = Hwr + (size_t)(myrow0 + r)*HID + colW;
            __hip_atomic_store(p, h16, __ATOMIC_RELAXED, __HIP_MEMORY_SCOPE_AGENT);
        }
        asm volatile("s_waitcnt vmcnt(0)" ::: "memory");
        __syncthreads();

        // ---- grid barrier: per-block flag (device scope), coalesced poll ----
        if (tid == 0)
            __hip_atomic_store(&flags[bid], (unsigned)(t+1), __ATOMIC_RELAXED, __HIP_MEMORY_SCOPE_AGENT);
        if (w == 0){
            unsigned tgt = (unsigned)(t+1), guard = 0;
            for (;;){
                unsigned f0 = __hip_atomic_load(&flags[l      ], __ATOMIC_RELAXED, __HIP_MEMORY_SCOPE_AGENT);
                unsigned f1 = __hip_atomic_load(&flags[l +  64], __ATOMIC_RELAXED, __HIP_MEMORY_SCOPE_AGENT);
                unsigned f2 = __hip_atomic_load(&flags[l + 128], __ATOMIC_RELAXED, __HIP_MEMORY_SCOPE_AGENT);
                unsigned f3 = __hip_atomic_load(&flags[l + 192], __ATOMIC_RELAXED, __HIP_MEMORY_SCOPE_AGENT);
                bool ok = (f0 >= tgt) && (f1 >= tgt) && (f2 >= tgt) && (f3 >= tgt);
                if (__all(ok)) break;
                if (++guard > 2000000u){ s_bail = 1; break; }
                __builtin_amdgcn_s_sleep(1);
            }
        }
        __syncthreads();
        if (s_bail) break;

        // ---- drop stale cached H lines before next step's plain loads.
        //      acquire fence at agent scope -> buffer_inv (no writeback).
        //      Every wave fences so each wave's own loads are ordered. ----
        __builtin_amdgcn_fence(__ATOMIC_ACQUIRE, "agent");
        __builtin_amdgcn_sched_barrier(0);
    }

    // ---- final dense: H(final, in Ha) @ dense_w + dense_b -> out[256][2] ----
    if (cg == 0 && !s_bail){
        int r = tid >> 2, j = (tid >> 1) & 1, half = tid & 1;
        int row = bg*64 + r;
        const f16* hrow = Ha + (size_t)row*HID + half*512;
        float s = 0.f;
        for (int v = 0; v < 64; v++){
            f16x8 h8;
            asm volatile("global_load_dwordx4 %0, %1, off sc1" : "=v"(h8) : "v"(hrow + v*8));
            asm volatile("s_waitcnt vmcnt(0)" ::: "memory");
            #pragma unroll
            for (int e = 0; e < 8; e++)
                s += (float)h8[e] * dw[(size_t)(half*512 + v*8 + e)*2 + j];
        }
        s += __shfl_xor(s, 1, 64);
        if (half == 0) out[(size_t)row*2 + j] = s + db[j];
    }
}

extern "C" void kernel_launch(void* const* d_in, const int* in_sizes, int n_in,
                              void* d_out, int out_size, void* d_ws, size_t ws_size,
                              hipStream_t stream)
{
    const int*   tokens = (const int*)d_in[0];
    const float* H0  = (const float*)d_in[1];
    const float* C0  = (const float*)d_in[2];
    const float* Wxi = (const float*)d_in[3];
    const float* Whi = (const float*)d_in[4];
    const float* bi  = (const float*)d_in[5];
    const float* Wxf = (const float*)d_in[6];
    const float* Whf = (const float*)d_in[7];
    const float* bf  = (const float*)d_in[8];
    const float* Wxo = (const float*)d_in[9];
    const float* Who = (const float*)d_in[10];
    const float* bo  = (const float*)d_in[11];
    const float* Wxc = (const float*)d_in[12];
    const float* Whc = (const float*)d_in[13];
    const float* bc  = (const float*)d_in[14];
    const float* emb = (const float*)d_in[15];
    const float* dw  = (const float*)d_in[16];
    const float* db  = (const float*)d_in[17];
    float* out = (float*)d_out;

    char* ws = (char*)d_ws;
    size_t off = 0;
    auto alloc = [&](size_t bytes){ void* p = ws + off; off += (bytes + 255) & ~(size_t)255; return p; };
    f16* WThi = (f16*)alloc((size_t)4096*KTOT*2);
    f16* WTlo = (f16*)alloc((size_t)4096*KTOT*2);
    f16* Xbuf = (f16*)alloc((size_t)STEPS*BATCHN*XPAD*2);
    f16* Ha   = (f16*)alloc((size_t)BATCHN*HID*2);
    f16* Hb   = (f16*)alloc((size_t)BATCHN*HID*2);
    float* biasP = (float*)alloc(4096*sizeof(float));
    unsigned* flags = (unsigned*)alloc(NBLK*sizeof(unsigned));
    if (off > ws_size) return;   // workspace too small: fail loud

    hipMemsetAsync(flags, 0, NBLK*sizeof(unsigned), stream);
    pack_w<<<4096, 256, 0, stream>>>(Whi,Whf,Who,Whc, Wxi,Wxf,Wxo,Wxc, bi,bf,bo,bc,
                                     WThi, WTlo, biasP);
    pack_x<<<STEPS*BATCHN, 128, 0, stream>>>(tokens, emb, Xbuf);
    pack_h0<<<(BATCHN*HID + 255)/256, 256, 0, stream>>>(H0, Ha);
    lstm_main<<<NBLK, 256, 0, stream>>>(WThi, WTlo, Xbuf, biasP, C0, Ha, Hb,
                                        dw, db, out, flags);
}

// Round 8
// 7167.819 us; speedup vs baseline: 1.4676x; 1.4676x over previous
//
#include <hip/hip_runtime.h>

typedef _Float16 f16;
typedef _Float16 f16x8 __attribute__((ext_vector_type(8)));
typedef float f32x4 __attribute__((ext_vector_type(4)));

#define STEPS 512
#define BATCHN 256
#define HID 1024
#define EMBN 100
#define KTOT 1152
#define XPAD 128
#define NBLK 256

__device__ __forceinline__ float sigm(float x){ return 1.f/(1.f+__expf(-x)); }
__device__ __forceinline__ float tanh_f(float x){
    float e = __expf(2.f*fabsf(x));
    float r = 1.f - 2.f/(e+1.f);
    return x >= 0.f ? r : -r;
}
// select {a0,a1,a2,a3}[idx] without runtime-indexed array (rule #20)
__device__ __forceinline__ float pick4(float a0, float a1, float a2, float a3, int idx){
    float t0 = (idx & 1) ? a1 : a0;
    float t1 = (idx & 1) ? a3 : a2;
    return (idx & 2) ? t1 : t0;
}

// Pack W_h(1024 rows)+W_x(100)+pad -> WT[4096][1152] f16 hi/lo.
// Col J = cg*64 + ct*16 + g*4 + um -> unit u = cg*16 + ct*4 + um. Also bias[J].
__global__ void pack_w(const float* __restrict__ Whi_, const float* __restrict__ Whf_,
                       const float* __restrict__ Who_, const float* __restrict__ Whc_,
                       const float* __restrict__ Wxi_, const float* __restrict__ Wxf_,
                       const float* __restrict__ Wxo_, const float* __restrict__ Wxc_,
                       const float* __restrict__ bi_, const float* __restrict__ bf_,
                       const float* __restrict__ bo_, const float* __restrict__ bc_,
                       f16* __restrict__ WThi, f16* __restrict__ WTlo, float* __restrict__ biasP)
{
    int J = blockIdx.x;                 // 0..4095
    int cg = J >> 6, ct = (J >> 4) & 3, g = (J >> 2) & 3, um = J & 3;
    int u = cg*16 + ct*4 + um;
    const float* Wh = (g==0)?Whi_:(g==1)?Whf_:(g==2)?Who_:Whc_;
    const float* Wx = (g==0)?Wxi_:(g==1)?Wxf_:(g==2)?Wxo_:Wxc_;
    for (int k = threadIdx.x; k < KTOT; k += blockDim.x){
        float v = 0.f;
        if (k < 1024)       v = Wh[(size_t)k*HID + u];
        else if (k < 1124)  v = Wx[(size_t)(k-1024)*HID + u];
        f16 hi = (f16)v;
        WThi[(size_t)J*KTOT + k] = hi;
        WTlo[(size_t)J*KTOT + k] = (f16)(v - (float)hi);
    }
    if (threadIdx.x == 0){
        const float* bb = (g==0)?bi_:(g==1)?bf_:(g==2)?bo_:bc_;
        biasP[J] = bb[u];
    }
}

__global__ void pack_x(const int* __restrict__ tokens, const float* __restrict__ emb,
                       f16* __restrict__ Xbuf)
{
    int bid = blockIdx.x;               // t*256 + row
    int t = bid >> 8, row = bid & 255;
    int tok = tokens[(size_t)row*STEPS + t];
    int kx = threadIdx.x;               // 0..127
    float v = (kx < EMBN) ? emb[(size_t)tok*EMBN + kx] : 0.f;
    Xbuf[(size_t)bid*XPAD + kx] = (f16)v;
}

__global__ void pack_h0(const float* __restrict__ H0, f16* __restrict__ Hb)
{
    int i = blockIdx.x*blockDim.x + threadIdx.x;
    if (i < BATCHN*HID) Hb[i] = (f16)H0[i];
}

// Async DMA: 16B/lane, LDS dest = wave-uniform base + lane*16 (linear).
// H: aux=16 (SC1 = device scope, LLC path — same scope as round-4's proven
// sc1 loads). X: aux=0 (immutable, plain cached — m97-proven semantics).
#define DMA16(gsrc, ldst, AUX)                                                     \
    __builtin_amdgcn_global_load_lds(                                              \
        (const __attribute__((address_space(1))) unsigned int*)(gsrc),             \
        (__attribute__((address_space(3))) unsigned int*)(ldst), 16, 0, (AUX))

// Stage one k-tile (64 rows x 32 k, 4KB) into wave-private slot via 4 DMA chunks.
// Chunk c: lane l -> row c*16+(l>>2), dst granule l&3, src granule (l&3)^(row&3)
// (source-side swizzle; DMA dest stays linear per m104/m173).
#define ISSUE_DMA(kt_, slot_) do {                                                 \
    const int kb_ = w*288 + (kt_)*32;                                              \
    f16* d0_ = AldsW + (slot_)*2048;                                               \
    if (kb_ < 1024){                                                               \
        DMA16(Hrd + srcH0 + kb_, d0_,        16);                                  \
        DMA16(Hrd + srcH1 + kb_, d0_ + 512,  16);                                  \
        DMA16(Hrd + srcH2 + kb_, d0_ + 1024, 16);                                  \
        DMA16(Hrd + srcH3 + kb_, d0_ + 1536, 16);                                  \
    } else {                                                                       \
        const int xo_ = kb_ - 1024;                                                \
        DMA16(Xrow + srcX0 + xo_, d0_,        0);                                  \
        DMA16(Xrow + srcX1 + xo_, d0_ + 512,  0);                                  \
        DMA16(Xrow + srcX2 + xo_, d0_ + 1024, 0);                                  \
        DMA16(Xrow + srcX3 + xo_, d0_ + 1536, 0);                                  \
    }                                                                              \
} while(0)

#define WAITV(kt_) do {                                                            \
    if ((kt_) < 7)       asm volatile("s_waitcnt vmcnt(8)" ::: "memory");          \
    else if ((kt_) == 7) asm volatile("s_waitcnt vmcnt(4)" ::: "memory");          \
    else                 asm volatile("s_waitcnt vmcnt(0)" ::: "memory");          \
    __builtin_amdgcn_sched_barrier(0);                                             \
} while(0)

#define LOADA(slot_, AF) do {                                                      \
    AF[0] = *(const f16x8*)(AldsW + (slot_)*2048 + ofsA0);                         \
    AF[1] = *(const f16x8*)(AldsW + (slot_)*2048 + ofsA1);                         \
    AF[2] = *(const f16x8*)(AldsW + (slot_)*2048 + ofsA2);                         \
    AF[3] = *(const f16x8*)(AldsW + (slot_)*2048 + ofsA3);                         \
} while(0)

#define MM(kt_, AF) do {                                                           \
    _Pragma("unroll")                                                              \
    for (int q_ = 0; q_ < 4; q_++){                                                \
        _Pragma("unroll")                                                          \
        for (int ct_ = 0; ct_ < 4; ct_++){                                         \
            acc[q_][ct_] = __builtin_amdgcn_mfma_f32_16x16x32_f16(AF[q_], Bf[kt_][0][ct_], acc[q_][ct_], 0,0,0); \
            acc[q_][ct_] = __builtin_amdgcn_mfma_f32_16x16x32_f16(AF[q_], Bf[kt_][1][ct_], acc[q_][ct_], 0,0,0); \
        }                                                                          \
    }                                                                              \
} while(0)

// Persistent LSTM: 256 blocks (4 bg x 64 cg) x 256 threads, 1/CU.
// Weights f16 hi/lo in VGPR+AGPR (288/lane). A staged via async global_load_lds
// (3-deep kt ring, ~12KB/wave in flight). H + flags at device scope (sc1/LLC).
// LDS total 48KB: the 16KB reduction buffer OVERLAYS the Alds ring (safe: a
// __syncthreads() separates the last Alds ds_read from the first red write, and
// the post-barrier sync separates the last red read from next step's DMA).
__global__ __launch_bounds__(256, 1) void lstm_main(
    const f16* __restrict__ WThi, const f16* __restrict__ WTlo,
    const f16* __restrict__ Xbuf, const float* __restrict__ biasP,
    const float* __restrict__ C0, f16* __restrict__ Ha, f16* __restrict__ Hb,
    const float* __restrict__ dw, const float* __restrict__ db,
    float* __restrict__ out, unsigned* __restrict__ flags)
{
    __shared__ __align__(16) f16 Alds[4*3*2048];   // 48KB; red overlays [0,16KB)
    __shared__ int s_bail;
    f32x4* red = (f32x4*)Alds;                      // [owner4][ct4][lane64]

    const int bid = blockIdx.x;
    const int bg = bid & 3, cg = bid >> 2;
    const int tid = threadIdx.x;
    const int w = tid >> 6, l = tid & 63, lr = l & 15, lhi = l >> 4;
    const int um = l & 3, gs = lr >> 2;
    if (tid == 0) s_bail = 0;

    f16* AldsW = Alds + w*3*2048;

    // ---- persistent weights: 9 kt x {hi,lo} x 4 ct = 288 VGPR/AGPR per lane ----
    f16x8 Bf[9][2][4];
    #pragma unroll
    for (int kt = 0; kt < 9; kt++){
        int k0 = w*288 + kt*32 + lhi*8;
        #pragma unroll
        for (int ct = 0; ct < 4; ct++){
            size_t off = (size_t)(cg*64 + ct*16 + lr)*KTOT + k0;
            Bf[kt][0][ct] = *(const f16x8*)(WThi + off);
            Bf[kt][1][ct] = *(const f16x8*)(WTlo + off);
        }
    }
    float bs[4][4];                      // [ct][gate]
    #pragma unroll
    for (int ct = 0; ct < 4; ct++)
        #pragma unroll
        for (int g = 0; g < 4; g++)
            bs[ct][g] = biasP[cg*64 + ct*16 + g*4 + um];

    // DMA source per-lane offsets (f16 units). Chunk c: row = c*16 + (l>>2),
    // source granule swizzle ((l&3)^((l>>2)&3))*8.
    const int swz = ((l & 3) ^ ((l >> 2) & 3))*8;
    const int rl4 = l >> 2;
    const int srcH0 = (bg*64 +  0 + rl4)*HID + swz;
    const int srcH1 = (bg*64 + 16 + rl4)*HID + swz;
    const int srcH2 = (bg*64 + 32 + rl4)*HID + swz;
    const int srcH3 = (bg*64 + 48 + rl4)*HID + swz;
    const int srcX0 = (bg*64 +  0 + rl4)*XPAD + swz;
    const int srcX1 = (bg*64 + 16 + rl4)*XPAD + swz;
    const int srcX2 = (bg*64 + 32 + rl4)*XPAD + swz;
    const int srcX3 = (bg*64 + 48 + rl4)*XPAD + swz;

    // ds_read offsets: row = ((w+q)&3)*16 + lr; granule = lhi ^ (row&3) = lhi ^ (lr&3)
    const int gsw = (lhi ^ (lr & 3)) << 3;
    const int ofsA0 = (((w + 0) & 3)*16 + lr)*32 + gsw;
    const int ofsA1 = (((w + 1) & 3)*16 + lr)*32 + gsw;
    const int ofsA2 = (((w + 2) & 3)*16 + lr)*32 + gsw;
    const int ofsA3 = (((w + 3) & 3)*16 + lr)*32 + gsw;

    const int myrow0 = bg*64 + w*16 + lhi*4;      // kept rowtile = global rt w
    const int colW = cg*16 + gs*4 + um;           // H-store column

    float Cr[4][4];                      // [ct][r], gs-redundant
    #pragma unroll
    for (int ct = 0; ct < 4; ct++)
        #pragma unroll
        for (int r = 0; r < 4; r++)
            Cr[ct][r] = C0[(size_t)(myrow0 + r)*HID + cg*16 + ct*4 + um];

    __syncthreads();

    for (int t = 0; t < STEPS; t++){
        const f16* Hrd = (t & 1) ? Hb : Ha;
        f16*       Hwr = (t & 1) ? Ha : Hb;
        const f16* Xrow = Xbuf + (size_t)t*BATCHN*XPAD;

        f32x4 acc[4][4];
        #pragma unroll
        for (int q = 0; q < 4; q++)
            #pragma unroll
            for (int ct = 0; ct < 4; ct++) acc[q][ct] = (f32x4){0.f,0.f,0.f,0.f};

        // ---- A staging + MFMA: 3-deep async DMA kt-ring (wave-private slots) ----
        ISSUE_DMA(0, 0);
        ISSUE_DMA(1, 1);
        #pragma unroll
        for (int kt = 0; kt < 9; kt++){
            const int slot = kt % 3;
            if (kt < 7) ISSUE_DMA(kt + 2, (kt + 2) % 3);
            WAITV(kt);
            f16x8 Af[4];
            LOADA(slot, Af);
            MM(kt, Af);
        }

        // ---- all Alds reads done before red overlay writes ----
        __syncthreads();

        // ---- cross-wave K reduction in 3 owner-phases (red overlays Alds) ----
        #pragma unroll
        for (int p = 1; p <= 3; p++){
            int o = (w + p) & 3;
            #pragma unroll
            for (int ct = 0; ct < 4; ct++)
                red[(o*4 + ct)*64 + l] = acc[p][ct];
            __syncthreads();
            #pragma unroll
            for (int ct = 0; ct < 4; ct++)
                acc[0][ct] += red[(w*4 + ct)*64 + l];
            if (p < 3) __syncthreads();
        }

        // ---- epilogue: gather gates (xor 4/8/12), update C, compute h ----
        float hall[4][4];
        #pragma unroll
        for (int ct = 0; ct < 4; ct++){
            #pragma unroll
            for (int r = 0; r < 4; r++){
                float a0 = acc[0][ct][r];
                float a1 = __shfl_xor(a0, 4, 64);
                float a2 = __shfl_xor(a0, 8, 64);
                float a3 = __shfl_xor(a0, 12, 64);
                float gi = pick4(a0,a1,a2,a3, gs    ) + bs[ct][0];
                float gf = pick4(a0,a1,a2,a3, gs ^ 1) + bs[ct][1];
                float go = pick4(a0,a1,a2,a3, gs ^ 2) + bs[ct][2];
                float gc = pick4(a0,a1,a2,a3, gs ^ 3) + bs[ct][3];
                float I = sigm(gi), F = sigm(gf), O = sigm(go), G = tanh_f(gc);
                float c = F*Cr[ct][r] + I*G;
                Cr[ct][r] = c;
                hall[ct][r] = O*tanh_f(c);
            }
        }

        // ---- H store: lane gs stores ct=gs -> each (unit,row) exactly once.
        //      Device scope (sc1 write-through to LLC). ----
        #pragma unroll
        for (int r = 0; r < 4; r++){
            float hv = pick4(hall[0][r], hall[1][r], hall[2][r], hall[3][r], gs);
            f16 h16 = (f16)hv;
            f16* p = Hwr + (size_t)(myrow0 + r)*HID + colW;
            __hip_atomic_store(p, h16, __ATOMIC_RELAXED, __HIP_MEMORY_SCOPE_AGENT);
        }
        asm volatile("s_waitcnt vmcnt(0)" ::: "memory");
        __syncthreads();

        // ---- grid barrier: per-block flag (device scope), coalesced poll ----
        if (tid == 0)
            __hip_atomic_store(&flags[bid], (unsigned)(t+1), __ATOMIC_RELAXED, __HIP_MEMORY_SCOPE_AGENT);
        if (w == 0){
            unsigned tgt = (unsigned)(t+1), guard = 0;
            for (;;){
                unsigned f0 = __hip_atomic_load(&flags[l      ], __ATOMIC_RELAXED, __HIP_MEMORY_SCOPE_AGENT);
                unsigned f1 = __hip_atomic_load(&flags[l +  64], __ATOMIC_RELAXED, __HIP_MEMORY_SCOPE_AGENT);
                unsigned f2 = __hip_atomic_load(&flags[l + 128], __ATOMIC_RELAXED, __HIP_MEMORY_SCOPE_AGENT);
                unsigned f3 = __hip_atomic_load(&flags[l + 192], __ATOMIC_RELAXED, __HIP_MEMORY_SCOPE_AGENT);
                bool ok = (f0 >= tgt) && (f1 >= tgt) && (f2 >= tgt) && (f3 >= tgt);
                if (__all(ok)) break;
                if (++guard > 2000000u){ s_bail = 1; break; }
                __builtin_amdgcn_s_sleep(1);
            }
        }
        __syncthreads();
        if (s_bail) break;
    }

    // ---- final dense: H(final, in Ha) @ dense_w + dense_b -> out[256][2] ----
    if (cg == 0){
        int r = tid >> 2, j = (tid >> 1) & 1, half = tid & 1;
        int row = bg*64 + r;
        const f16* hrow = Ha + (size_t)row*HID + half*512;
        float s = 0.f;
        for (int v = 0; v < 64; v++){
            f16x8 h8;
            asm volatile("global_load_dwordx4 %0, %1, off sc1" : "=v"(h8) : "v"(hrow + v*8));
            asm volatile("s_waitcnt vmcnt(0)" ::: "memory");
            #pragma unroll
            for (int e = 0; e < 8; e++)
                s += (float)h8[e] * dw[(size_t)(half*512 + v*8 + e)*2 + j];
        }
        s += __shfl_xor(s, 1, 64);
        if (half == 0) out[(size_t)row*2 + j] = s + db[j];
    }
}

extern "C" void kernel_launch(void* const* d_in, const int* in_sizes, int n_in,
                              void* d_out, int out_size, void* d_ws, size_t ws_size,
                              hipStream_t stream)
{
    const int*   tokens = (const int*)d_in[0];
    const float* H0  = (const float*)d_in[1];
    const float* C0  = (const float*)d_in[2];
    const float* Wxi = (const float*)d_in[3];
    const float* Whi = (const float*)d_in[4];
    const float* bi  = (const float*)d_in[5];
    const float* Wxf = (const float*)d_in[6];
    const float* Whf = (const float*)d_in[7];
    const float* bf  = (const float*)d_in[8];
    const float* Wxo = (const float*)d_in[9];
    const float* Who = (const float*)d_in[10];
    const float* bo  = (const float*)d_in[11];
    const float* Wxc = (const float*)d_in[12];
    const float* Whc = (const float*)d_in[13];
    const float* bc  = (const float*)d_in[14];
    const float* emb = (const float*)d_in[15];
    const float* dw  = (const float*)d_in[16];
    const float* db  = (const float*)d_in[17];
    float* out = (float*)d_out;

    char* ws = (char*)d_ws;
    size_t off = 0;
    auto alloc = [&](size_t bytes){ void* p = ws + off; off += (bytes + 255) & ~(size_t)255; return p; };
    f16* WThi = (f16*)alloc((size_t)4096*KTOT*2);
    f16* WTlo = (f16*)alloc((size_t)4096*KTOT*2);
    f16* Xbuf = (f16*)alloc((size_t)STEPS*BATCHN*XPAD*2);
    f16* Ha   = (f16*)alloc((size_t)BATCHN*HID*2);
    f16* Hb   = (f16*)alloc((size_t)BATCHN*HID*2);
    float* biasP = (float*)alloc(4096*sizeof(float));
    unsigned* flags = (unsigned*)alloc(NBLK*sizeof(unsigned));
    if (off > ws_size) return;   // workspace too small: fail loud

    hipMemsetAsync(flags, 0, NBLK*sizeof(unsigned), stream);
    pack_w<<<4096, 256, 0, stream>>>(Whi,Whf,Who,Whc, Wxi,Wxf,Wxo,Wxc, bi,bf,bo,bc,
                                     WThi, WTlo, biasP);
    pack_x<<<STEPS*BATCHN, 128, 0, stream>>>(tokens, emb, Xbuf);
    pack_h0<<<(BATCHN*HID + 255)/256, 256, 0, stream>>>(H0, Ha);
    lstm_main<<<NBLK, 256, 0, stream>>>(WThi, WTlo, Xbuf, biasP, C0, Ha, Hb,
                                        dw, db, out, flags);
}